// Round 7
// baseline (218.192 us; speedup 1.0000x reference)
//
#include <hip/hip_runtime.h>
#include <hip/hip_bf16.h>
#include <stdint.h>

typedef unsigned short u16;
typedef __bf16 bf16x8 __attribute__((ext_vector_type(8)));
typedef float f32x4 __attribute__((ext_vector_type(4)));

#define MFMA16(a, b, c) __builtin_amdgcn_mfma_f32_16x16x32_bf16((a), (b), (c), 0, 0, 0)

#define GLOAD16(g, l)                                                        \
  __builtin_amdgcn_global_load_lds(                                          \
      (const __attribute__((address_space(1))) void*)(g),                    \
      (__attribute__((address_space(3))) void*)(l), 16, 0, 0)

static __device__ __forceinline__ u16 f2bf(float f) {
  union { float f; uint32_t u; } v;
  v.f = f;
  uint32_t u = v.u;
  return (u16)((u + 0x7FFFu + ((u >> 16) & 1u)) >> 16);  // RNE
}
static __device__ __forceinline__ float bf2f(u16 u) {
  union { uint32_t u; float f; } v;
  v.u = ((uint32_t)u) << 16;
  return v.f;
}

// ---- workspace layout (u16 elements) ----
#define FEATT_ELEMS (8u * 98u * 98u * 256u)   // [b][h+1][w+1][c] bf16, zero halo
#define W1T_OFF     FEATT_ELEMS               // [oc][tap][cin] bf16: 256*2304
#define W1T_ELEMS   (256u * 2304u)
#define W2B_OFF     (W1T_OFF + W1T_ELEMS)     // [576][256] bf16

// ---------------- halo zeroing (halo is 1.6MB) ------------
__global__ __launch_bounds__(256) void halo_zero(u16* __restrict__ featT) {
  int tid = blockIdx.x * 256 + threadIdx.x;  // 8 * 388 * 32 = 99328 threads
  int b = tid / (388 * 32);
  int rem = tid % (388 * 32);
  int pos = rem >> 5, v = rem & 31;
  int h, w;
  if (pos < 98) { h = 0; w = pos; }
  else if (pos < 196) { h = 97; w = pos - 98; }
  else if (pos < 292) { h = pos - 196 + 1; w = 0; }
  else { h = pos - 292 + 1; w = 97; }
  uint4* dst = (uint4*)(featT + (size_t)((b * 98 + h) * 98 + w) * 256 + v * 8);
  *dst = make_uint4(0, 0, 0, 0);
}

// ---------------- prep: feat NCHW f32 -> featT [b][h+1][w+1][c] bf16 -------------
__global__ __launch_bounds__(256) void prep_featT(const float* __restrict__ feat,
                                                  u16* __restrict__ featT) {
  const int pt = blockIdx.x, ct = blockIdx.y, b = blockIdx.z;
  const int p0 = pt * 64, c0 = ct * 64;
  __shared__ float tile[64][65];
  const int t = threadIdx.x;
  const int pj = t & 63, ci0 = t >> 6;
#pragma unroll
  for (int r = 0; r < 16; ++r) {
    int ci = r * 4 + ci0;
    tile[ci][pj] = feat[(b * 256 + c0 + ci) * 9216 + p0 + pj];
  }
  __syncthreads();
  const int pl = t >> 2, cc0 = (t & 3) * 16;
  const int pix = p0 + pl;
  const int h = pix / 96, w = pix % 96;
  uint32_t u[8];
#pragma unroll
  for (int i = 0; i < 8; ++i) {
    u16 lo = f2bf(tile[cc0 + 2 * i][pl]);
    u16 hi = f2bf(tile[cc0 + 2 * i + 1][pl]);
    u[i] = (uint32_t)lo | ((uint32_t)hi << 16);
  }
  uint4* dst = (uint4*)(featT + (size_t)((b * 98 + h + 1) * 98 + (w + 1)) * 256 + c0 + cc0);
  dst[0] = make_uint4(u[0], u[1], u[2], u[3]);
  dst[1] = make_uint4(u[4], u[5], u[6], u[7]);
}

// ---------------- prep: weights -> bf16 (w1 reordered to [oc][tap][cin]) ---------
__global__ __launch_bounds__(256) void prep_w(const float* __restrict__ w1,
                                              const float* __restrict__ w2,
                                              u16* __restrict__ w1t,
                                              u16* __restrict__ w2b) {
  int i = blockIdx.x * 256 + threadIdx.x;
  if (i < 589824) {
    int oc = i / 2304, r = i % 2304;
    int tap = r >> 8, cin = r & 255;
    w1t[i] = f2bf(w1[(oc * 256 + cin) * 9 + tap]);
  } else {
    int j = i - 589824;
    if (j < 147456) w2b[j] = f2bf(w2[j]);
  }
}

// =================== FUSED: conv3x3+relu -> 1x1 -> softmax -> combine ===========
// BM=128 px, BN=256, BK=64, 8 waves (2Mx4N). Phase A = r2-gemm1 structure verbatim
// (single-buffer 48KB, plain __syncthreads loop -- 770 TF proven).
// LDS lifetime reuse:  [0,24576) A-tiles  ->  [0,32768) sX  ->  [0,18432) B2 dbuf.
// sFlow bf16 at [32768,35072).  Total 70.1 KB -> 2 blocks/CU (16 waves/CU).
__global__ __launch_bounds__(512, 4) void fused(const u16* __restrict__ featT,
                                                const u16* __restrict__ w1t,
                                                const float* __restrict__ b1g,
                                                const u16* __restrict__ w2b,
                                                const float* __restrict__ b2g,
                                                const float* __restrict__ flow,
                                                float* __restrict__ out) {
  __shared__ __align__(16) u16 smem[35072];  // 70144 B

  const int t = threadIdx.x;
  const int wave = t >> 6, lane = t & 63;
  const int bid = blockIdx.x;
  const int mt = (bid & 7) * 72 + (bid >> 3);  // bijective XCD swizzle (576%8==0)
  const int b = mt / 72;
  const int ipl0 = (mt % 72) * 128;  // image-LOCAL pixel base (0..9088)

  // ---- sFlow (bf16) fill: [2][9][128] at 32768 ----
  for (int i = t; i < 2304; i += 512) {
    int c = i / 1152, rem = i % 1152;
    int k = rem >> 7, p = rem & 127;
    int ip = ipl0 + p;
    int h = ip / 96, w = ip % 96;
    int hh = h + k / 3 - 1, ww = w + k % 3 - 1;
    float v = 0.f;
    if (hh >= 0 && hh < 96 && ww >= 0 && ww < 96)
      v = flow[((b * 2 + c) * 96 + hh) * 96 + ww];
    smem[32768 + i] = f2bf(v);
  }

  // ---- phase A staging bases (r2-gemm1 verbatim) ----
  const u16* aBase[2];
#pragma unroll
  for (int r = 0; r < 2; ++r) {
    int row = r * 64 + wave * 8 + (lane >> 3);  // 0..127
    int chunk = (lane & 7) ^ (row & 7);
    int ip = ipl0 + row;
    int h = ip / 96, w = ip % 96;
    aBase[r] = featT + (size_t)((b * 98 + h + 1) * 98 + (w + 1)) * 256 + chunk * 8;
  }
  const u16* bBase[4];
#pragma unroll
  for (int r = 0; r < 4; ++r) {
    int row = wave * 32 + r * 8 + (lane >> 3);  // 0..255
    int chunk = (lane & 7) ^ (row & 7);
    bBase[r] = w1t + (size_t)row * 2304 + chunk * 8;
  }

  const int wm = wave >> 2, wn = wave & 3;
  const int l15 = lane & 15, kc = lane >> 4;
  int aoffs[4][2], boffs[4][2];
#pragma unroll
  for (int m = 0; m < 4; ++m) {
#pragma unroll
    for (int ki = 0; ki < 2; ++ki) {
      int kcc = ki * 4 + kc;
      int rowa = wm * 64 + m * 16 + l15;
      aoffs[m][ki] = rowa * 64 + ((kcc ^ (rowa & 7)) * 8);
      int rowb = wn * 64 + m * 16 + l15;
      boffs[m][ki] = 8192 + rowb * 64 + ((kcc ^ (rowb & 7)) * 8);
    }
  }

  f32x4 acc[4][4];
#pragma unroll
  for (int m = 0; m < 4; ++m)
#pragma unroll
    for (int n = 0; n < 4; ++n) acc[m][n] = f32x4{0.f, 0.f, 0.f, 0.f};

  for (int kt = 0; kt < 36; ++kt) {
    int tap = kt >> 2;
    int dh = tap / 3 - 1, dw = tap % 3 - 1;
    int aoff = (dh * 98 + dw) * 256 + (kt & 3) * 64;
    int boff = kt * 64;
#pragma unroll
    for (int r = 0; r < 2; ++r) GLOAD16(aBase[r] + aoff, &smem[(r * 64 + wave * 8) * 64]);
#pragma unroll
    for (int r = 0; r < 4; ++r)
      GLOAD16(bBase[r] + boff, &smem[8192 + (wave * 32 + r * 8) * 64]);
    __syncthreads();  // tile ready (compiler drains vmcnt before barrier)
#pragma unroll
    for (int ki = 0; ki < 2; ++ki) {
      bf16x8 av[4], bv[4];
#pragma unroll
      for (int m = 0; m < 4; ++m) av[m] = *(const bf16x8*)&smem[aoffs[m][ki]];
#pragma unroll
      for (int n = 0; n < 4; ++n) bv[n] = *(const bf16x8*)&smem[boffs[n][ki]];
#pragma unroll
      for (int m = 0; m < 4; ++m)
#pragma unroll
        for (int n = 0; n < 4; ++n) acc[m][n] = MFMA16(av[m], bv[n], acc[m][n]);
    }
    __syncthreads();  // reads done before next stage overwrites
  }

  // ---- epilogue A: bias+relu -> sX[pix][256] at [0,32768) (chunk-XOR sigma=pix&7) ----
  const int g4 = kc << 2;
#pragma unroll
  for (int m = 0; m < 4; ++m) {
    int pixr = wm * 64 + m * 16 + g4;
#pragma unroll
    for (int n = 0; n < 4; ++n) {
      int oc = wn * 64 + n * 16 + l15;
      float bias = b1g[oc];
      f32x4 v = acc[m][n];
#pragma unroll
      for (int j = 0; j < 4; ++j) {
        int pix = pixr + j;
        float val = v[j] + bias;
        val = val > 0.f ? val : 0.f;
        smem[pix * 256 + (((oc >> 3) ^ (pix & 7)) * 8) + (oc & 7)] = f2bf(val);
      }
    }
  }
  __syncthreads();  // sX complete

  // ---- areg extraction: each wave's 16 pixels, full K=256 ----
  bf16x8 areg[8];
  const int pixl = wave * 16 + l15;  // 0..127
#pragma unroll
  for (int s = 0; s < 8; ++s) {
    int kco = s * 4 + kc;  // oc chunk 0..31
    areg[s] = *(const bf16x8*)&smem[pixl * 256 + ((kco ^ (pixl & 7)) * 8)];
  }
  __syncthreads();  // sX dead; [0,18432) becomes B2 dbuf

  // ---- phase C: B2 staging (144 virt-n x 64 k per step, 18KB, dbuf) ----
  auto stageC = [&](int cI, int kk, int bufi) {
    u16* db = &smem[bufi * 9216];
#pragma unroll
    for (int i = 0; i < 3; ++i) {
      int g = i * 8 + wave;  // wave-uniform predicate
      if (g < 18) {
        int n = g * 8 + (lane >> 3);  // virtual n, 0..143
        int chan = (n >> 4) * 64 + cI * 16 + (n & 15);
        int cs = (lane & 7) ^ (n & 7);
        GLOAD16(w2b + (size_t)chan * 256 + kk * 64 + cs * 8, db + g * 512);
      }
    }
  };

  stageC(0, 0, 0);
  __syncthreads();  // B2 step-0 landed

  f32x4 acc2[9];
#pragma unroll
  for (int cI = 0; cI < 4; ++cI) {
#pragma unroll
    for (int kk = 0; kk < 4; ++kk) {
      const int s = cI * 4 + kk;
      const int bufi = s & 1;
      if (s < 15) {
        int s1 = s + 1;
        stageC(s1 >> 2, s1 & 3, bufi ^ 1);
      }
      if (kk == 0) {
#pragma unroll
        for (int nf = 0; nf < 9; ++nf) acc2[nf] = f32x4{0.f, 0.f, 0.f, 0.f};
      }
      const u16* base = &smem[bufi * 9216];
#pragma unroll
      for (int ki = 0; ki < 2; ++ki) {
        bf16x8 a = areg[kk * 2 + ki];  // static index (fully unrolled)
        int kc2 = ki * 4 + kc;         // 0..7
#pragma unroll
        for (int nf = 0; nf < 9; ++nf) {
          int n = nf * 16 + l15;
          bf16x8 bv = *(const bf16x8*)&base[n * 64 + ((kc2 ^ (n & 7)) * 8)];
          acc2[nf] = MFMA16(a, bv, acc2[nf]);
        }
      }
      if (kk == 3) {
        // softmax + flow-combine + pixel-shuffle store for this cI (16 pq)
        int pql = l15;
        int p = cI * 2 + (pql >> 3), q = pql & 7;
#pragma unroll
        for (int j = 0; j < 4; ++j) {
          int pe = wave * 16 + g4 + j;  // 0..127
          float v[9], mx = -3.0e38f;
#pragma unroll
          for (int nf = 0; nf < 9; ++nf) {
            v[nf] = acc2[nf][j] + b2g[nf * 64 + cI * 16 + pql];
            mx = fmaxf(mx, v[nf]);
          }
          float ssum = 0.f, fx = 0.f, fy = 0.f;
#pragma unroll
          for (int nf = 0; nf < 9; ++nf) {
            float e = __expf(v[nf] - mx);
            ssum += e;
            fx += e * bf2f(smem[32768 + nf * 128 + pe]);
            fy += e * bf2f(smem[32768 + 1152 + nf * 128 + pe]);
          }
          float sc = 8.0f / ssum;
          int ip = ipl0 + pe;
          int h = ip / 96, w = ip % 96;
          size_t o0 = ((size_t)(b * 2 + 0) * 768 + h * 8 + p) * 768 + w * 8 + q;
          size_t o1 = ((size_t)(b * 2 + 1) * 768 + h * 8 + p) * 768 + w * 8 + q;
          out[o0] = fx * sc;
          out[o1] = fy * sc;
        }
      }
      __syncthreads();  // buf reads done; next-step data landed
    }
  }
}

extern "C" void kernel_launch(void* const* d_in, const int* in_sizes, int n_in,
                              void* d_out, int out_size, void* d_ws, size_t ws_size,
                              hipStream_t stream) {
  const float* flow = (const float*)d_in[0];
  const float* feat = (const float*)d_in[1];
  const float* w1 = (const float*)d_in[2];
  const float* b1 = (const float*)d_in[3];
  const float* w2 = (const float*)d_in[4];
  const float* b2 = (const float*)d_in[5];
  float* out = (float*)d_out;
  u16* ws = (u16*)d_ws;
  u16* featT = ws;
  u16* w1t = ws + W1T_OFF;
  u16* w2b = ws + W2B_OFF;

  halo_zero<<<388, 256, 0, stream>>>(featT);
  prep_featT<<<dim3(144, 4, 8), 256, 0, stream>>>(feat, featT);
  prep_w<<<2880, 256, 0, stream>>>(w1, w2, w1t, w2b);
  fused<<<576, 512, 0, stream>>>(featT, w1t, b1, w2b, b2, flow, out);
}